// Round 1
// baseline (304.599 us; speedup 1.0000x reference)
//
#include <hip/hip_runtime.h>

#define HW 3136
#define NB 32
#define NC 128

__global__ __launch_bounds__(256, 4)
void mvg_kernel(const float* __restrict__ emb, float* __restrict__ out) {
  const int pos = blockIdx.x;
  const int t = threadIdx.x;

  __shared__ float Xs[NB * NC];       // 16 KB slice
  __shared__ float rowbuf[2][NC];     // pivot-row broadcast, double buffered
  __shared__ float ms[NC];            // mean

  // ---- gather the (B, C) slice for this position (strided; L2/L3 absorbs) ----
  #pragma unroll
  for (int m = 0; m < 16; ++m) {
    const int idx = t + 256 * m;
    const int b = idx >> 7;
    const int c = idx & (NC - 1);
    Xs[idx] = emb[(size_t)b * ((size_t)NC * HW) + (size_t)c * HW + pos];
  }
  __syncthreads();

  // ---- mean over batch, write mean output ----
  if (t < NC) {
    float s = 0.f;
    #pragma unroll
    for (int b = 0; b < NB; ++b) s += Xs[b * NC + t];
    const float m = s * (1.0f / NB);
    ms[t] = m;
    out[(size_t)t * HW + pos] = m;
  }
  __syncthreads();

  // ---- center in LDS ----
  #pragma unroll
  for (int m = 0; m < 16; ++m) {
    const int idx = t + 256 * m;
    Xs[idx] -= ms[idx & (NC - 1)];
  }
  __syncthreads();

  // ---- per-thread 8x8 tile: rows [i0,i0+8), cols [c0,c0+8) ----
  const int i0 = (t >> 4) << 3;
  const int c0 = (t & 15) << 3;

  float4 a0[8], a1[8];
  #pragma unroll
  for (int r = 0; r < 8; ++r) {
    a0[r] = make_float4(0.f, 0.f, 0.f, 0.f);
    a1[r] = make_float4(0.f, 0.f, 0.f, 0.f);
  }

  #define FMA_TILE(CR, RV0, RV1)                                         \
    _Pragma("unroll")                                                    \
    for (int r = 0; r < 8; ++r) {                                        \
      const float cc = CR[r];                                            \
      a0[r].x = fmaf(cc, RV0.x, a0[r].x);                                \
      a0[r].y = fmaf(cc, RV0.y, a0[r].y);                                \
      a0[r].z = fmaf(cc, RV0.z, a0[r].z);                                \
      a0[r].w = fmaf(cc, RV0.w, a0[r].w);                                \
      a1[r].x = fmaf(cc, RV1.x, a1[r].x);                                \
      a1[r].y = fmaf(cc, RV1.y, a1[r].y);                                \
      a1[r].z = fmaf(cc, RV1.z, a1[r].z);                                \
      a1[r].w = fmaf(cc, RV1.w, a1[r].w);                                \
    }

  // ---- covariance accumulate ----
  for (int b = 0; b < NB; ++b) {
    const float* xr = &Xs[b * NC];
    const float4 rv0 = *(const float4*)&xr[c0];
    const float4 rv1 = *(const float4*)&xr[c0 + 4];
    const float4 cv0 = *(const float4*)&xr[i0];
    const float4 cv1 = *(const float4*)&xr[i0 + 4];
    const float cr[8] = {cv0.x, cv0.y, cv0.z, cv0.w, cv1.x, cv1.y, cv1.z, cv1.w};
    FMA_TILE(cr, rv0, rv1)
  }

  // ---- scale by 1/(B-1), add (REG_DIAG + REG_EPS) on the diagonal ----
  {
    const float s31 = 1.0f / (float)(NB - 1);
    const float RD = 0.01f + 1e-5f;
    #pragma unroll
    for (int r = 0; r < 8; ++r) {
      const int gr = i0 + r;
      a0[r].x = a0[r].x * s31 + ((gr == c0 + 0) ? RD : 0.f);
      a0[r].y = a0[r].y * s31 + ((gr == c0 + 1) ? RD : 0.f);
      a0[r].z = a0[r].z * s31 + ((gr == c0 + 2) ? RD : 0.f);
      a0[r].w = a0[r].w * s31 + ((gr == c0 + 3) ? RD : 0.f);
      a1[r].x = a1[r].x * s31 + ((gr == c0 + 4) ? RD : 0.f);
      a1[r].y = a1[r].y * s31 + ((gr == c0 + 5) ? RD : 0.f);
      a1[r].z = a1[r].z * s31 + ((gr == c0 + 6) ? RD : 0.f);
      a1[r].w = a1[r].w * s31 + ((gr == c0 + 7) ? RD : 0.f);
    }
  }

  // ---- init pivot-row broadcast with row 0; slot k holds (d - 1) ----
  if (t < 16) {                      // i0 == 0, local row r = 0
    *(float4*)&rowbuf[0][c0] = a0[0];
    *(float4*)&rowbuf[0][c0 + 4] = a1[0];
    if (c0 == 0) rowbuf[0][0] -= 1.0f;
  }
  __syncthreads();

  // ---- sweep: 128 pivots, one barrier each; result is -A^{-1} (+2 on diag) ----
  int cur = 0;
  for (int k = 0; k < NC; ++k) {
    const float* rb = rowbuf[cur];
    float* wb = rowbuf[cur ^ 1];
    const float dm1 = rb[k];                       // d - 1 (broadcast)
    const float rd = __builtin_amdgcn_rcpf(dm1 + 1.0f);
    const float4 rv0 = *(const float4*)&rb[c0];
    const float4 rv1 = *(const float4*)&rb[c0 + 4];
    const float4 cv0 = *(const float4*)&rb[i0];
    const float4 cv1 = *(const float4*)&rb[i0 + 4];
    const float nci[8] = {-(cv0.x * rd), -(cv0.y * rd), -(cv0.z * rd), -(cv0.w * rd),
                          -(cv1.x * rd), -(cv1.y * rd), -(cv1.z * rd), -(cv1.w * rd)};
    FMA_TILE(nci, rv0, rv1)

    const int kk = k + 1;
    if (kk < NC && (unsigned)(kk - i0) < 8u) {     // owner threads of pivot row k+1
      #pragma unroll
      for (int r = 0; r < 8; ++r) {
        if (r == kk - i0) {
          *(float4*)&wb[c0] = a0[r];
          *(float4*)&wb[c0 + 4] = a1[r];
        }
      }
      if ((unsigned)(kk - c0) < 8u) wb[kk] -= 1.0f;  // store d-1 in slot kk
    }
    __syncthreads();
    cur ^= 1;
  }

  // ---- store inverse: inv = -reg, diagonal = 2 - reg (undo +2 corruption) ----
  float* o = out + (size_t)NC * HW + (size_t)pos * (NC * NC);
  #pragma unroll
  for (int r = 0; r < 8; ++r) {
    const int gr = i0 + r;
    float4 w0, w1;
    w0.x = (gr == c0 + 0) ? (2.0f - a0[r].x) : (-a0[r].x);
    w0.y = (gr == c0 + 1) ? (2.0f - a0[r].y) : (-a0[r].y);
    w0.z = (gr == c0 + 2) ? (2.0f - a0[r].z) : (-a0[r].z);
    w0.w = (gr == c0 + 3) ? (2.0f - a0[r].w) : (-a0[r].w);
    w1.x = (gr == c0 + 4) ? (2.0f - a1[r].x) : (-a1[r].x);
    w1.y = (gr == c0 + 5) ? (2.0f - a1[r].y) : (-a1[r].y);
    w1.z = (gr == c0 + 6) ? (2.0f - a1[r].z) : (-a1[r].z);
    w1.w = (gr == c0 + 7) ? (2.0f - a1[r].w) : (-a1[r].w);
    *(float4*)&o[(size_t)gr * NC + c0] = w0;
    *(float4*)&o[(size_t)gr * NC + c0 + 4] = w1;
  }
}

extern "C" void kernel_launch(void* const* d_in, const int* in_sizes, int n_in,
                              void* d_out, int out_size, void* d_ws, size_t ws_size,
                              hipStream_t stream) {
  const float* emb = (const float*)d_in[0];
  float* out = (float*)d_out;
  mvg_kernel<<<HW, 256, 0, stream>>>(emb, out);
}